// Round 4
// baseline (2038.582 us; speedup 1.0000x reference)
//
#include <hip/hip_runtime.h>
#include <hip/hip_bf16.h>
#include <cmath>

#define C_IN 128
#define NKEY 32
#define N_H 4
#define D_H 32
#define C_BEV 256
#define H_Y 180
#define W_X 180
#define LDK16 (C_IN + 8)  // padded bf16 LDS stride

typedef __attribute__((ext_vector_type(8))) short short8;
typedef __attribute__((ext_vector_type(4))) float f32x4;

__device__ __forceinline__ float gelu_exact(float x) {
    return 0.5f * x * (1.0f + erff(x * 0.7071067811865475f));
}

__device__ __forceinline__ float dot4(float4 a, float4 b) {
    return a.x * b.x + a.y * b.y + a.z * b.z + a.w * b.w;
}

__device__ __forceinline__ float bf2f(ushort u) {
    union { unsigned int i; float f; } c; c.i = ((unsigned int)u) << 16; return c.f;
}

__device__ __forceinline__ ushort f2bf(float x) {
    __hip_bfloat16 h = __float2bfloat16(x);
    return *reinterpret_cast<ushort*>(&h);
}

// ---- prep: convert w_in rows [128,384) (wk|wv) to bf16 row-major [256][128]
__global__ void conv_wkv(const float* __restrict__ w_in, ushort* __restrict__ wbf) {
    const int i = blockIdx.x * 256 + threadIdx.x;
    if (i < 256 * C_IN) wbf[i] = f2bf(w_in[C_IN * C_IN + i]);
}

__global__ __launch_bounds__(256) void gridbev_fused(
    const float* __restrict__ vf,        // NV x 128
    const int*   __restrict__ spi,       // NV x 4 (b,z,y,x)
    const int*   __restrict__ ni,        // M x 4 (b,0,y,x)
    const int*   __restrict__ kidx,      // M x 32
    const float* __restrict__ bev,       // B x 256 x 180 x 180
    const ushort* __restrict__ wbf,      // 256 x 128 bf16 (wk|wv)
    const float* __restrict__ w_pos, const float* __restrict__ b_pos,
    const float* __restrict__ w_bev, const float* __restrict__ b_bev,
    const float* __restrict__ g_q,  const float* __restrict__ be_q,
    const float* __restrict__ g_k,  const float* __restrict__ be_k,
    const float* __restrict__ g_f,  const float* __restrict__ be_f,
    const float* __restrict__ w_in, const float* __restrict__ b_in,
    const float* __restrict__ w_out, const float* __restrict__ b_out,
    const float* __restrict__ w_fc1, const float* __restrict__ b_fc1,
    const float* __restrict__ w_fc2, const float* __restrict__ b_fc2,
    float* __restrict__ out)             // B x 128 x 180 x 180
{
    const int m   = blockIdx.x;
    const int tid = threadIdx.x;

    __shared__ ushort kf16 [NKEY][LDK16];   // LN'd key features, bf16 (MFMA A)
    __shared__ ushort khs16[NKEY][LDK16];   // key projections, bf16
    __shared__ ushort vhs16[NKEY][LDK16];   // value projections, bf16
    __shared__ float bevf[C_BEV];
    __shared__ float sc  [C_IN];            // shortcut
    __shared__ float qln [C_IN];
    __shared__ float qhs [C_IN];
    __shared__ float attnw[N_H][NKEY];
    __shared__ float avs [C_IN];
    __shared__ float xfs [C_IN];
    __shared__ float ylns[C_IN];
    __shared__ float h1s [C_IN];
    __shared__ int   kmsk[NKEY];

    // ---- issue independent gathers as early as possible
    const int nb = ni[m * 4 + 0];
    const int ny = ni[m * 4 + 2];
    const int nx = ni[m * 4 + 3];
    const float bevreg = bev[(((size_t)nb * C_BEV + tid) * H_Y + ny) * W_X + nx];

    const float qx = (nx + 0.5f) * (150.4f / 180.0f) - 75.2f;
    const float qy = (ny + 0.5f) * (150.4f / 180.0f) - 75.2f;
    const float qz = 1.0f;   // (0 + 0.5) * 6.0 - 2.0

    // ---- Phase 1: gather key feats + pos-emb GELU + LayerNorm_k -> kf16 (bf16)
    {
        const int p  = tid >> 3;        // 32 keys, 8 threads each
        const int g  = tid & 7;
        const int c0 = g * 16;
        const int kv = kidx[m * NKEY + p];
        if (g == 0) kmsk[p] = (kv < 0) ? 1 : 0;
        const int safe = (kv < 0) ? 0 : kv;
        const int sz = spi[safe * 4 + 1];
        const int sy = spi[safe * 4 + 2];
        const int sx = spi[safe * 4 + 3];
        const float cx = (sx + 0.5f) * (150.4f / 1440.0f) - 75.2f - qx;
        const float cy = (sy + 0.5f) * (150.4f / 1440.0f) - 75.2f - qy;
        const float cz = (sz + 0.5f) * (6.0f / 40.0f)     - 2.0f  - qz;

        float v[16];
        const float4* src = (const float4*)(vf + (size_t)safe * C_IN + c0);
        #pragma unroll
        for (int j = 0; j < 4; ++j) {
            float4 t = src[j];
            v[j*4+0] = t.x; v[j*4+1] = t.y; v[j*4+2] = t.z; v[j*4+3] = t.w;
        }
        #pragma unroll
        for (int j = 0; j < 16; ++j) {
            const int c = c0 + j;
            float e = cx * w_pos[c*3+0] + cy * w_pos[c*3+1] + cz * w_pos[c*3+2] + b_pos[c];
            v[j] += gelu_exact(e);
        }
        float s = 0.f;
        #pragma unroll
        for (int j = 0; j < 16; ++j) s += v[j];
        s += __shfl_xor(s, 1); s += __shfl_xor(s, 2); s += __shfl_xor(s, 4);
        const float mean = s * (1.0f / 128.0f);
        float vv = 0.f;
        #pragma unroll
        for (int j = 0; j < 16; ++j) { float d = v[j] - mean; vv += d * d; }
        vv += __shfl_xor(vv, 1); vv += __shfl_xor(vv, 2); vv += __shfl_xor(vv, 4);
        const float rs = rsqrtf(vv * (1.0f / 128.0f) + 1e-5f);
        ushort o[16];
        #pragma unroll
        for (int j = 0; j < 16; ++j) {
            const int c = c0 + j;
            o[j] = f2bf((v[j] - mean) * rs * g_k[c] + be_k[c]);
        }
        short8* drow = (short8*)(&kf16[p][c0]);
        drow[0] = *(short8*)&o[0];
        drow[1] = *(short8*)&o[8];
    }

    // ---- Phase 2a: stash BEV channels
    bevf[tid] = bevreg;
    __syncthreads();

    // ---- Phase KV (MFMA): [kh|vh] = kf16 @ wbf^T + bias -> khs16 / vhs16
    {
        const int wave = tid >> 6, lane = tid & 63;
        const int lhi = lane >> 4, llo = lane & 15;
        f32x4 acc[2][4];
        #pragma unroll
        for (int r = 0; r < 2; ++r)
            #pragma unroll
            for (int c = 0; c < 4; ++c)
                acc[r][c] = (f32x4){0.f, 0.f, 0.f, 0.f};

        #pragma unroll
        for (int kk = 0; kk < 4; ++kk) {
            const int koff = kk * 32 + lhi * 8;
            short8 afr[2];
            #pragma unroll
            for (int r = 0; r < 2; ++r)
                afr[r] = *(const short8*)&kf16[r * 16 + llo][koff];
            #pragma unroll
            for (int c = 0; c < 4; ++c) {
                const int ch = wave * 64 + c * 16 + llo;     // 0..255
                short8 bfr = *(const short8*)&wbf[(size_t)ch * C_IN + koff];
                #pragma unroll
                for (int r = 0; r < 2; ++r)
                    acc[r][c] = __builtin_amdgcn_mfma_f32_16x16x32_bf16(
                        afr[r], bfr, acc[r][c], 0, 0, 0);
            }
        }
        // writeback (bf16): C/D layout col=lane&15, row=(lane>>4)*4+q
        #pragma unroll
        for (int c = 0; c < 4; ++c) {
            const int ch = wave * 64 + c * 16 + llo;
            const float bias = b_in[C_IN + ch];
            ushort* dst = (ch < C_IN) ? &khs16[0][0] + ch : &vhs16[0][0] + (ch - C_IN);
            #pragma unroll
            for (int r = 0; r < 2; ++r) {
                #pragma unroll
                for (int q = 0; q < 4; ++q) {
                    const int key = r * 16 + lhi * 4 + q;
                    dst[key * LDK16] = f2bf(acc[r][c][q] + bias);
                }
            }
        }
    }

    // ---- Phase 2b: shortcut = gelu(bev @ w_bev^T + b_bev)
    {
        const int c = tid >> 1, half = tid & 1;
        const float4* wr = (const float4*)(w_bev + (size_t)c * C_BEV + half * 128);
        const float4* br = (const float4*)(bevf + half * 128);
        float acc = 0.f;
        #pragma unroll
        for (int k = 0; k < 32; ++k) acc += dot4(wr[k], br[k]);
        acc += __shfl_xor(acc, 1);
        if (half == 0) sc[c] = gelu_exact(acc + b_bev[c]);
    }
    __syncthreads();

    // ---- Phase 2c: q = LN(shortcut)
    {
        const int lane = tid & 63;
        const float v0 = sc[lane], v1 = sc[lane + 64];
        float s = v0 + v1;
        #pragma unroll
        for (int o = 32; o >= 1; o >>= 1) s += __shfl_xor(s, o);
        const float mean = s * (1.0f / 128.0f);
        const float d0 = v0 - mean, d1 = v1 - mean;
        float vv = d0 * d0 + d1 * d1;
        #pragma unroll
        for (int o = 32; o >= 1; o >>= 1) vv += __shfl_xor(vv, o);
        const float rs = rsqrtf(vv * (1.0f / 128.0f) + 1e-5f);
        if (tid < 128) {
            const float myv = (tid < 64) ? v0 : v1;
            qln[tid] = (myv - mean) * rs * g_q[tid] + be_q[tid];
        }
    }
    __syncthreads();

    // ---- Phase 3: qh = qln @ wq^T + bq
    {
        const int c = tid >> 1, half = tid & 1;
        const float4* wr = (const float4*)(w_in + (size_t)c * C_IN + half * 64);
        const float4* qr = (const float4*)(qln + half * 64);
        float acc = 0.f;
        #pragma unroll
        for (int k = 0; k < 16; ++k) acc += dot4(wr[k], qr[k]);
        acc += __shfl_xor(acc, 1);
        if (half == 0) qhs[c] = acc + b_in[c];
    }
    __syncthreads();

    // ---- Phase 5: logits + masked softmax (head h, key p per thread)
    if (tid < 128) {
        const int h = tid >> 5, p = tid & 31;
        const ushort* kr = &khs16[p][h * D_H];
        const float*  qr = qhs + h * D_H;
        float d = 0.f;
        #pragma unroll
        for (int j = 0; j < D_H; ++j) d += qr[j] * bf2f(kr[j]);
        const int msk = kmsk[p];
        float logit = msk ? -3.0e38f : d * 0.17677669529663687f;  // 1/sqrt(32)
        float mx = logit;
        #pragma unroll
        for (int o = 16; o >= 1; o >>= 1) mx = fmaxf(mx, __shfl_xor(mx, o));
        const float e = msk ? 0.0f : expf(logit - mx);
        float ssum = e;
        #pragma unroll
        for (int o = 16; o >= 1; o >>= 1) ssum += __shfl_xor(ssum, o);
        attnw[h][p] = e / ssum;
    }
    __syncthreads();

    // ---- Phase 6: av = attn @ vh
    if (tid < 128) {
        const int h = tid >> 5, d = tid & 31;
        float acc = 0.f;
        #pragma unroll
        for (int p = 0; p < NKEY; ++p) acc += attnw[h][p] * bf2f(vhs16[p][h * D_H + d]);
        avs[tid] = acc;
    }
    __syncthreads();

    // ---- attend = av @ w_out^T + b_out; xf = attend + shortcut
    {
        const int c = tid >> 1, half = tid & 1;
        const float4* wr = (const float4*)(w_out + (size_t)c * C_IN + half * 64);
        const float4* ar = (const float4*)(avs + half * 64);
        float acc = 0.f;
        #pragma unroll
        for (int k = 0; k < 16; ++k) acc += dot4(wr[k], ar[k]);
        acc += __shfl_xor(acc, 1);
        if (half == 0) xfs[c] = acc + b_out[c] + sc[c];
    }
    __syncthreads();

    // ---- LN(xf) -> ylns
    {
        const int lane = tid & 63;
        const float v0 = xfs[lane], v1 = xfs[lane + 64];
        float s = v0 + v1;
        #pragma unroll
        for (int o = 32; o >= 1; o >>= 1) s += __shfl_xor(s, o);
        const float mean = s * (1.0f / 128.0f);
        const float d0 = v0 - mean, d1 = v1 - mean;
        float vv = d0 * d0 + d1 * d1;
        #pragma unroll
        for (int o = 32; o >= 1; o >>= 1) vv += __shfl_xor(vv, o);
        const float rs = rsqrtf(vv * (1.0f / 128.0f) + 1e-5f);
        if (tid < 128) {
            const float myv = (tid < 64) ? v0 : v1;
            ylns[tid] = (myv - mean) * rs * g_f[tid] + be_f[tid];
        }
    }
    __syncthreads();

    // ---- fc1
    {
        const int c = tid >> 1, half = tid & 1;
        const float4* wr = (const float4*)(w_fc1 + (size_t)c * C_IN + half * 64);
        const float4* yr = (const float4*)(ylns + half * 64);
        float acc = 0.f;
        #pragma unroll
        for (int k = 0; k < 16; ++k) acc += dot4(wr[k], yr[k]);
        acc += __shfl_xor(acc, 1);
        if (half == 0) h1s[c] = gelu_exact(acc + b_fc1[c]);
    }
    __syncthreads();

    // ---- fc2 + residual, scatter to dense output
    {
        const int c = tid >> 1, half = tid & 1;
        const float4* wr = (const float4*)(w_fc2 + (size_t)c * C_IN + half * 64);
        const float4* hr = (const float4*)(h1s + half * 64);
        float acc = 0.f;
        #pragma unroll
        for (int k = 0; k < 16; ++k) acc += dot4(wr[k], hr[k]);
        acc += __shfl_xor(acc, 1);
        if (half == 0) {
            const float feat = acc + b_fc2[c] + xfs[c];
            out[(((size_t)nb * C_IN + c) * H_Y + ny) * W_X + nx] = feat;
        }
    }
}

extern "C" void kernel_launch(void* const* d_in, const int* in_sizes, int n_in,
                              void* d_out, int out_size, void* d_ws, size_t ws_size,
                              hipStream_t stream) {
    const float* vf    = (const float*)d_in[0];
    const int*   spi   = (const int*)  d_in[1];
    const int*   ni    = (const int*)  d_in[2];
    const int*   kidx  = (const int*)  d_in[3];
    const float* bev   = (const float*)d_in[4];
    const float* w_pos = (const float*)d_in[5];
    const float* b_pos = (const float*)d_in[6];
    const float* w_bev = (const float*)d_in[7];
    const float* b_bev = (const float*)d_in[8];
    const float* g_q   = (const float*)d_in[9];
    const float* be_q  = (const float*)d_in[10];
    const float* g_k   = (const float*)d_in[11];
    const float* be_k  = (const float*)d_in[12];
    const float* g_f   = (const float*)d_in[13];
    const float* be_f  = (const float*)d_in[14];
    const float* w_in  = (const float*)d_in[15];
    const float* b_in  = (const float*)d_in[16];
    const float* w_out = (const float*)d_in[17];
    const float* b_out = (const float*)d_in[18];
    const float* w_fc1 = (const float*)d_in[19];
    const float* b_fc1 = (const float*)d_in[20];
    const float* w_fc2 = (const float*)d_in[21];
    const float* b_fc2 = (const float*)d_in[22];
    float* out = (float*)d_out;
    ushort* wbf = (ushort*)d_ws;   // 256*128*2 = 64 KiB of scratch

    const int M = in_sizes[3] / NKEY;

    hipMemsetAsync(d_out, 0, (size_t)out_size * sizeof(float), stream);
    conv_wkv<<<128, 256, 0, stream>>>(w_in, wbf);

    gridbev_fused<<<M, 256, 0, stream>>>(
        vf, spi, ni, kidx, bev, wbf, w_pos, b_pos, w_bev, b_bev,
        g_q, be_q, g_k, be_k, g_f, be_f, w_in, b_in,
        w_out, b_out, w_fc1, b_fc1, w_fc2, b_fc2, out);
}

// Round 6
// 1820.889 us; speedup vs baseline: 1.1196x; 1.1196x over previous
//
#include <hip/hip_runtime.h>
#include <hip/hip_bf16.h>
#include <cmath>

#define C_IN 128
#define NKEY 32
#define N_H 4
#define D_H 32
#define C_BEV 256
#define H_Y 180
#define W_X 180
#define LDK16 (C_IN + 8)  // padded bf16 LDS stride

typedef __attribute__((ext_vector_type(8))) short short8;
typedef __attribute__((ext_vector_type(4))) float f32x4;

__device__ __forceinline__ float gelu_exact(float x) {
    return 0.5f * x * (1.0f + erff(x * 0.7071067811865475f));
}

__device__ __forceinline__ float dot4(float4 a, float4 b) {
    return a.x * b.x + a.y * b.y + a.z * b.z + a.w * b.w;
}

__device__ __forceinline__ float bf2f(ushort u) {
    union { unsigned int i; float f; } c; c.i = ((unsigned int)u) << 16; return c.f;
}

__device__ __forceinline__ ushort f2bf(float x) {
    __hip_bfloat16 h = __float2bfloat16(x);
    return *reinterpret_cast<ushort*>(&h);
}

// ---- prep: convert w_in rows [128,384) (wk|wv) to bf16 row-major [256][128]
__global__ void conv_wkv(const float* __restrict__ w_in, ushort* __restrict__ wbf) {
    const int i = blockIdx.x * 256 + threadIdx.x;
    if (i < 256 * C_IN) wbf[i] = f2bf(w_in[C_IN * C_IN + i]);
}

// 2 queries per 512-thread block: amortizes weight-fetch latency + barriers.
__global__ __launch_bounds__(512, 4) void gridbev_fused(
    const float* __restrict__ vf,        // NV x 128
    const int*   __restrict__ spi,       // NV x 4 (b,z,y,x)
    const int*   __restrict__ ni,        // M x 4 (b,0,y,x)
    const int*   __restrict__ kidx,      // M x 32
    const float* __restrict__ bev,       // B x 256 x 180 x 180
    const ushort* __restrict__ wbf,      // 256 x 128 bf16 (wk|wv)
    const float* __restrict__ w_pos, const float* __restrict__ b_pos,
    const float* __restrict__ w_bev, const float* __restrict__ b_bev,
    const float* __restrict__ g_q,  const float* __restrict__ be_q,
    const float* __restrict__ g_k,  const float* __restrict__ be_k,
    const float* __restrict__ g_f,  const float* __restrict__ be_f,
    const float* __restrict__ w_in, const float* __restrict__ b_in,
    const float* __restrict__ w_out, const float* __restrict__ b_out,
    const float* __restrict__ w_fc1, const float* __restrict__ b_fc1,
    const float* __restrict__ w_fc2, const float* __restrict__ b_fc2,
    float* __restrict__ out,             // B x 128 x 180 x 180
    const int M)
{
    const int m2  = blockIdx.x * 2;
    const int tid = threadIdx.x;

    __shared__ ushort kf16 [2*NKEY][LDK16];   // LN'd key feats, bf16 (MFMA A)
    __shared__ ushort khs16[2*NKEY][LDK16];   // key projections, bf16
    __shared__ ushort vhs16[2*NKEY][LDK16];   // value projections, bf16
    __shared__ float bevf[2][C_BEV];
    __shared__ float sc  [2][C_IN];
    __shared__ float qln [2][C_IN];
    __shared__ float qhs [2][C_IN];
    __shared__ float attnw[2][N_H][NKEY];
    __shared__ float avs [2][C_IN];
    __shared__ float xfs [2][C_IN];
    __shared__ float ylns[2][C_IN];
    __shared__ float h1s [2][C_IN];
    __shared__ int   kmsk[2*NKEY];

    // ---- per-block query indices (q1 clamped for odd tail; store guarded)
    const int mA = m2;
    const int mB = (m2 + 1 < M) ? (m2 + 1) : (M - 1);
    const int nbA = ni[mA*4+0], nyA = ni[mA*4+2], nxA = ni[mA*4+3];
    const int nbB = ni[mB*4+0], nyB = ni[mB*4+2], nxB = ni[mB*4+3];

    // ---- early independent gather: bev channels (q = tid>>8, ch = tid&255)
    const int qg  = tid >> 8;
    const int cch = tid & 255;
    const int nbg = qg ? nbB : nbA, nyg = qg ? nyB : nyA, nxg = qg ? nxB : nxA;
    const float bevreg = bev[(((size_t)nbg * C_BEV + cch) * H_Y + nyg) * W_X + nxg];

    // ---- Phase 1: 64 keys x 8 threads: gather + posemb GELU + LN_k -> kf16
    {
        const int kk = tid >> 3;          // 0..63 (key slot; q = kk>>5)
        const int qk = kk >> 5;
        const int g  = tid & 7;
        const int c0 = g * 16;
        const int mq = qk ? mB : mA;
        const int nxk = qk ? nxB : nxA, nyk = qk ? nyB : nyA;
        const float qxk = (nxk + 0.5f) * (150.4f / 180.0f) - 75.2f;
        const float qyk = (nyk + 0.5f) * (150.4f / 180.0f) - 75.2f;

        const int kv = kidx[mq * NKEY + (kk & 31)];
        if (g == 0) kmsk[kk] = (kv < 0) ? 1 : 0;
        const int safe = (kv < 0) ? 0 : kv;
        const int sz = spi[safe * 4 + 1];
        const int sy = spi[safe * 4 + 2];
        const int sx = spi[safe * 4 + 3];
        const float cx = (sx + 0.5f) * (150.4f / 1440.0f) - 75.2f - qxk;
        const float cy = (sy + 0.5f) * (150.4f / 1440.0f) - 75.2f - qyk;
        const float cz = (sz + 0.5f) * (6.0f / 40.0f)     - 2.0f  - 1.0f;

        float v[16];
        const float4* src = (const float4*)(vf + (size_t)safe * C_IN + c0);
        #pragma unroll
        for (int j = 0; j < 4; ++j) {
            float4 t = src[j];
            v[j*4+0] = t.x; v[j*4+1] = t.y; v[j*4+2] = t.z; v[j*4+3] = t.w;
        }
        #pragma unroll
        for (int j = 0; j < 16; ++j) {
            const int c = c0 + j;
            float e = cx * w_pos[c*3+0] + cy * w_pos[c*3+1] + cz * w_pos[c*3+2] + b_pos[c];
            v[j] += gelu_exact(e);
        }
        float s = 0.f;
        #pragma unroll
        for (int j = 0; j < 16; ++j) s += v[j];
        s += __shfl_xor(s, 1); s += __shfl_xor(s, 2); s += __shfl_xor(s, 4);
        const float mean = s * (1.0f / 128.0f);
        float vv = 0.f;
        #pragma unroll
        for (int j = 0; j < 16; ++j) { float d = v[j] - mean; vv += d * d; }
        vv += __shfl_xor(vv, 1); vv += __shfl_xor(vv, 2); vv += __shfl_xor(vv, 4);
        const float rs = rsqrtf(vv * (1.0f / 128.0f) + 1e-5f);
        ushort o[16];
        #pragma unroll
        for (int j = 0; j < 16; ++j) {
            const int c = c0 + j;
            o[j] = f2bf((v[j] - mean) * rs * g_k[c] + be_k[c]);
        }
        short8* drow = (short8*)(&kf16[kk][c0]);
        drow[0] = *(short8*)&o[0];
        drow[1] = *(short8*)&o[8];
    }

    bevf[qg][cch] = bevreg;
    __syncthreads();                                   // barrier 1

    // ---- Phase KV (MFMA, 8 waves): [kh|vh](64 keys x 256) = kf16 @ wbf^T
    {
        const int wv = tid >> 6, lane = tid & 63;
        const int lhi = lane >> 4, llo = lane & 15;
        f32x4 acc[4][2];
        #pragma unroll
        for (int r = 0; r < 4; ++r)
            #pragma unroll
            for (int c = 0; c < 2; ++c)
                acc[r][c] = (f32x4){0.f, 0.f, 0.f, 0.f};

        #pragma unroll
        for (int kk4 = 0; kk4 < 4; ++kk4) {
            const int koff = kk4 * 32 + lhi * 8;
            short8 afr[4];
            #pragma unroll
            for (int r = 0; r < 4; ++r)
                afr[r] = *(const short8*)&kf16[r * 16 + llo][koff];
            #pragma unroll
            for (int c = 0; c < 2; ++c) {
                const int ch = wv * 32 + c * 16 + llo;       // 0..255
                short8 bfr = *(const short8*)&wbf[(size_t)ch * C_IN + koff];
                #pragma unroll
                for (int r = 0; r < 4; ++r)
                    acc[r][c] = __builtin_amdgcn_mfma_f32_16x16x32_bf16(
                        afr[r], bfr, acc[r][c], 0, 0, 0);
            }
        }
        // writeback (bf16): C/D layout col=lane&15, row=(lane>>4)*4+q
        #pragma unroll
        for (int c = 0; c < 2; ++c) {
            const int ch = wv * 32 + c * 16 + llo;
            const float bias = b_in[C_IN + ch];
            ushort* dst = (ch < C_IN) ? &khs16[0][0] + ch : &vhs16[0][0] + (ch - C_IN);
            #pragma unroll
            for (int r = 0; r < 4; ++r) {
                #pragma unroll
                for (int qe = 0; qe < 4; ++qe) {
                    const int key = r * 16 + lhi * 4 + qe;
                    dst[key * LDK16] = f2bf(acc[r][c][qe] + bias);
                }
            }
        }
    }

    // ---- shortcut = gelu(bev @ w_bev^T + b_bev)  (q=tid>>8, 2 thr/ch)
    {
        const int q = tid >> 8, c = (tid >> 1) & 127, half = tid & 1;
        const float4* wr = (const float4*)(w_bev + (size_t)c * C_BEV + half * 128);
        const float4* br = (const float4*)(&bevf[q][half * 128]);
        float acc = 0.f;
        #pragma unroll
        for (int k = 0; k < 32; ++k) acc += dot4(wr[k], br[k]);
        acc += __shfl_xor(acc, 1);
        if (half == 0) sc[q][c] = gelu_exact(acc + b_bev[c]);
    }
    __syncthreads();                                   // barrier 2

    // ---- q = LN(shortcut) per query
    {
        const int q = tid >> 8, lane = tid & 63;
        const float v0 = sc[q][lane], v1 = sc[q][lane + 64];
        float s = v0 + v1;
        #pragma unroll
        for (int o = 32; o >= 1; o >>= 1) s += __shfl_xor(s, o);
        const float mean = s * (1.0f / 128.0f);
        const float d0 = v0 - mean, d1 = v1 - mean;
        float vv = d0 * d0 + d1 * d1;
        #pragma unroll
        for (int o = 32; o >= 1; o >>= 1) vv += __shfl_xor(vv, o);
        const float rs = rsqrtf(vv * (1.0f / 128.0f) + 1e-5f);
        if ((tid & 255) < 128) {
            const int idx = tid & 127;
            const float myv = (idx < 64) ? v0 : v1;
            qln[q][idx] = (myv - mean) * rs * g_q[idx] + be_q[idx];
        }
    }
    __syncthreads();                                   // barrier 3

    // ---- qh = qln @ wq^T + bq
    {
        const int q = tid >> 8, c = (tid >> 1) & 127, half = tid & 1;
        const float4* wr = (const float4*)(w_in + (size_t)c * C_IN + half * 64);
        const float4* qr = (const float4*)(&qln[q][half * 64]);
        float acc = 0.f;
        #pragma unroll
        for (int k = 0; k < 16; ++k) acc += dot4(wr[k], qr[k]);
        acc += __shfl_xor(acc, 1);
        if (half == 0) qhs[q][c] = acc + b_in[c];
    }
    __syncthreads();                                   // barrier 4

    // ---- logits + masked softmax: (q,h,p) per thread, tid<256
    if (tid < 256) {
        const int q = tid >> 7, h = (tid >> 5) & 3, p = tid & 31;
        const int kk2 = q * NKEY + p;
        const ushort* kr = &khs16[kk2][h * D_H];
        const float*  qr = &qhs[q][h * D_H];
        float d = 0.f;
        #pragma unroll
        for (int j = 0; j < D_H; ++j) d += qr[j] * bf2f(kr[j]);
        const int msk = kmsk[kk2];
        float logit = msk ? -3.0e38f : d * 0.17677669529663687f;  // 1/sqrt(32)
        float mx = logit;
        #pragma unroll
        for (int o = 16; o >= 1; o >>= 1) mx = fmaxf(mx, __shfl_xor(mx, o));
        const float e = msk ? 0.0f : expf(logit - mx);
        float ssum = e;
        #pragma unroll
        for (int o = 16; o >= 1; o >>= 1) ssum += __shfl_xor(ssum, o);
        attnw[q][h][p] = e / ssum;
    }
    __syncthreads();                                   // barrier 5

    // ---- av = attn @ vh: (q,h,d) per thread, tid<256
    if (tid < 256) {
        const int q = tid >> 7, h = (tid >> 5) & 3, d = tid & 31;
        float acc = 0.f;
        #pragma unroll
        for (int p = 0; p < NKEY; ++p)
            acc += attnw[q][h][p] * bf2f(vhs16[q * NKEY + p][h * D_H + d]);
        avs[q][h * D_H + d] = acc;
    }
    __syncthreads();                                   // barrier 6

    // ---- attend = av @ w_out^T + b_out; xf = attend + shortcut
    {
        const int q = tid >> 8, c = (tid >> 1) & 127, half = tid & 1;
        const float4* wr = (const float4*)(w_out + (size_t)c * C_IN + half * 64);
        const float4* ar = (const float4*)(&avs[q][half * 64]);
        float acc = 0.f;
        #pragma unroll
        for (int k = 0; k < 16; ++k) acc += dot4(wr[k], ar[k]);
        acc += __shfl_xor(acc, 1);
        if (half == 0) xfs[q][c] = acc + b_out[c] + sc[q][c];
    }
    __syncthreads();                                   // barrier 7

    // ---- LN(xf) -> ylns
    {
        const int q = tid >> 8, lane = tid & 63;
        const float v0 = xfs[q][lane], v1 = xfs[q][lane + 64];
        float s = v0 + v1;
        #pragma unroll
        for (int o = 32; o >= 1; o >>= 1) s += __shfl_xor(s, o);
        const float mean = s * (1.0f / 128.0f);
        const float d0 = v0 - mean, d1 = v1 - mean;
        float vv = d0 * d0 + d1 * d1;
        #pragma unroll
        for (int o = 32; o >= 1; o >>= 1) vv += __shfl_xor(vv, o);
        const float rs = rsqrtf(vv * (1.0f / 128.0f) + 1e-5f);
        if ((tid & 255) < 128) {
            const int idx = tid & 127;
            const float myv = (idx < 64) ? v0 : v1;
            ylns[q][idx] = (myv - mean) * rs * g_f[idx] + be_f[idx];
        }
    }
    __syncthreads();                                   // barrier 8

    // ---- fc1
    {
        const int q = tid >> 8, c = (tid >> 1) & 127, half = tid & 1;
        const float4* wr = (const float4*)(w_fc1 + (size_t)c * C_IN + half * 64);
        const float4* yr = (const float4*)(&ylns[q][half * 64]);
        float acc = 0.f;
        #pragma unroll
        for (int k = 0; k < 16; ++k) acc += dot4(wr[k], yr[k]);
        acc += __shfl_xor(acc, 1);
        if (half == 0) h1s[q][c] = gelu_exact(acc + b_fc1[c]);
    }
    __syncthreads();                                   // barrier 9

    // ---- fc2 + residual, scatter to dense output
    {
        const int q = tid >> 8, c = (tid >> 1) & 127, half = tid & 1;
        const float4* wr = (const float4*)(w_fc2 + (size_t)c * C_IN + half * 64);
        const float4* hr = (const float4*)(&h1s[q][half * 64]);
        float acc = 0.f;
        #pragma unroll
        for (int k = 0; k < 16; ++k) acc += dot4(wr[k], hr[k]);
        acc += __shfl_xor(acc, 1);
        if (half == 0 && (m2 + q) < M) {
            const int nb = q ? nbB : nbA, ny = q ? nyB : nyA, nx = q ? nxB : nxA;
            const float feat = acc + b_fc2[c] + xfs[q][c];
            out[(((size_t)nb * C_IN + c) * H_Y + ny) * W_X + nx] = feat;
        }
    }
}

extern "C" void kernel_launch(void* const* d_in, const int* in_sizes, int n_in,
                              void* d_out, int out_size, void* d_ws, size_t ws_size,
                              hipStream_t stream) {
    const float* vf    = (const float*)d_in[0];
    const int*   spi   = (const int*)  d_in[1];
    const int*   ni    = (const int*)  d_in[2];
    const int*   kidx  = (const int*)  d_in[3];
    const float* bev   = (const float*)d_in[4];
    const float* w_pos = (const float*)d_in[5];
    const float* b_pos = (const float*)d_in[6];
    const float* w_bev = (const float*)d_in[7];
    const float* b_bev = (const float*)d_in[8];
    const float* g_q   = (const float*)d_in[9];
    const float* be_q  = (const float*)d_in[10];
    const float* g_k   = (const float*)d_in[11];
    const float* be_k  = (const float*)d_in[12];
    const float* g_f   = (const float*)d_in[13];
    const float* be_f  = (const float*)d_in[14];
    const float* w_in  = (const float*)d_in[15];
    const float* b_in  = (const float*)d_in[16];
    const float* w_out = (const float*)d_in[17];
    const float* b_out = (const float*)d_in[18];
    const float* w_fc1 = (const float*)d_in[19];
    const float* b_fc1 = (const float*)d_in[20];
    const float* w_fc2 = (const float*)d_in[21];
    const float* b_fc2 = (const float*)d_in[22];
    float* out = (float*)d_out;
    ushort* wbf = (ushort*)d_ws;   // 256*128*2 = 64 KiB of scratch

    const int M = in_sizes[3] / NKEY;

    hipMemsetAsync(d_out, 0, (size_t)out_size * sizeof(float), stream);
    conv_wkv<<<128, 256, 0, stream>>>(w_in, wbf);

    gridbev_fused<<<(M + 1) / 2, 512, 0, stream>>>(
        vf, spi, ni, kidx, bev, wbf, w_pos, b_pos, w_bev, b_bev,
        g_q, be_q, g_k, be_k, g_f, be_f, w_in, b_in,
        w_out, b_out, w_fc1, b_fc1, w_fc2, b_fc2, out, M);
}